// Round 9
// baseline (330.871 us; speedup 1.0000x reference)
//
#include <hip/hip_runtime.h>
#include <stdint.h>

// Problem constants (CorrelationModule): x[8,384,48,48], O=512, N=48*48=2304
#define B_    8
#define CIN   384
#define OCH   512
#define NTOK  2304
#define SCALE 0.044194173824159216f  // 1/sqrt(512)

typedef unsigned short u16;
typedef u16   u16x8 __attribute__((ext_vector_type(8)));
typedef short s16x8 __attribute__((ext_vector_type(8)));
typedef float f32x4 __attribute__((ext_vector_type(4)));

// ---------- bf16 helpers (bit-level, RNE) ----------
__device__ __forceinline__ u16 f2bf(float f) {
    union { uint32_t i; float f; } v; v.f = f;
    uint32_t r = v.i + 0x7fffu + ((v.i >> 16) & 1u);
    return (u16)(r >> 16);
}

// ---------- async global->LDS (width 16) ----------
typedef __attribute__((address_space(1))) const uint32_t glb_u32;
typedef __attribute__((address_space(3))) uint32_t lds_u32;

__device__ __forceinline__ void gld16(const u16* g, u16* l) {
    __builtin_amdgcn_global_load_lds((glb_u32*)g, (lds_u32*)l, 16, 0, 0);
}

// =====================================================================
// BRICK FORMAT for all bf16 intermediates.
// brick (g, c) = rows g*16..+16, cols c*32..+32, 512 u16, chunk l (16 B)
// = (col8 = l>>4, row = l&15).  u16 offset of (row, col) inside brick:
//   ((col>>3)&3)*128 + (row&15)*8 + (col&7)
//
// R16 = R15 (verified 286.7 µs) with logits moved to a 1-wave 128x64
// pipelined kernel.  Evidence: 1-wave 64^2 won on qkv/pv/out (counted
// vmcnt, zero barriers, 6+ blocks/CU TLP) but lost on logits (85 vs
// 72.5) because AI was 2 MFMA/KB staged.  128x64 keeps the proven
// mechanism at 2.67 MFMA/KB (12 loads -> 32 MFMA per step, vmcnt(12)).
// =====================================================================
__device__ __forceinline__ size_t baddr(int row, int col, int Kc) {
    return ((size_t)(row >> 4) * (Kc >> 5) + (col >> 5)) * 512
         + (size_t)(((col >> 3) & 3) * 128 + (row & 15) * 8 + (col & 7));
}

// 16x16x32 MFMA core on brick buffers (proven R6/R7 algebra)
__device__ __forceinline__ void mfma_core(const u16* __restrict__ As,
                                          const u16* __restrict__ Bs,
                                          int wm16, int wn16, int lrow, int kq,
                                          f32x4 acc[4][4])
{
    s16x8 a[4], b[4];
#pragma unroll
    for (int i = 0; i < 4; ++i)
        a[i] = *(const s16x8*)(As + (((wm16 + i) * 64) + kq * 16 + lrow) * 8);
#pragma unroll
    for (int j = 0; j < 4; ++j)
        b[j] = *(const s16x8*)(Bs + (((wn16 + j) * 64) + kq * 16 + lrow) * 8);
#pragma unroll
    for (int i = 0; i < 4; ++i)
#pragma unroll
        for (int j = 0; j < 4; ++j)
            acc[i][j] = __builtin_amdgcn_mfma_f32_16x16x32_bf16(a[i], b[j], acc[i][j], 0, 0, 0);
}

// =====================================================================
// 1-wave 64x64 GEMM core (R14-verified).  MODE: 1 = +bias[col] (Q/K),
// 2 = +bias[row] (V), 3 = *1/rowsum[row] (pv), 4 = fp32 +bias[row] (out)
// =====================================================================
template <int MODE, int K>
__device__ __forceinline__ void gemm64_core(
    u16* __restrict__ sm,
    const u16* __restrict__ A, const u16* __restrict__ Bp,
    const float* __restrict__ aux, void* __restrict__ Cout,
    int N, int m0, int n0)
{
    constexpr int NT = K / 32;                 // 12 / 16 / 72 — all even
    u16* As0 = sm;
    u16* Bs0 = sm + 2048;
    u16* As1 = sm + 4096;
    u16* Bs1 = sm + 6144;

    const int ln = threadIdx.x & 63;
    const int lrow = ln & 15, kq = ln >> 4;

    const int bpr = K >> 5;
    const size_t rstep = (size_t)bpr << 9;     // one brick-row in u16
    const u16* pA = A  + (((size_t)(m0 >> 4) * bpr) << 9) + (size_t)(ln << 3);
    const u16* pB = Bp + (((size_t)(n0 >> 4) * bpr) << 9) + (size_t)(ln << 3);

    f32x4 acc[4][4] = {};

#define STAGE8(ga, gb, Ad, Bd)                                             \
    gld16((ga),             (Ad));        gld16((ga) + rstep,     (Ad) + 512);  \
    gld16((ga) + 2 * rstep, (Ad) + 1024); gld16((ga) + 3 * rstep, (Ad) + 1536); \
    gld16((gb),             (Bd));        gld16((gb) + rstep,     (Bd) + 512);  \
    gld16((gb) + 2 * rstep, (Bd) + 1024); gld16((gb) + 3 * rstep, (Bd) + 1536);

    STAGE8(pA, pB, As0, Bs0)                   // prologue: step 0 -> buf0

#pragma unroll 1
    for (int kt = 0; kt < NT; kt += 2) {
        STAGE8(pA + 512, pB + 512, As1, Bs1)   // step kt+1 -> buf1
        asm volatile("s_waitcnt vmcnt(8)" ::: "memory");   // step-kt loads done
        mfma_core(As0, Bs0, 0, 0, lrow, kq, acc);
        asm volatile("" ::: "memory");
        if (kt + 2 < NT) {
            STAGE8(pA + 1024, pB + 1024, As0, Bs0)         // step kt+2 -> buf0
            asm volatile("s_waitcnt vmcnt(8)" ::: "memory");
        } else {
            asm volatile("s_waitcnt vmcnt(0)" ::: "memory");
        }
        mfma_core(As1, Bs1, 0, 0, lrow, kq, acc);
        asm volatile("" ::: "memory");
        pA += 1024; pB += 1024;
    }
#undef STAGE8

    const int offl = ((lrow >> 3) << 7) + (lrow & 7) + (kq << 5);

    if constexpr (MODE == 1) {                 // col-bias, u16 brick
        u16* C = (u16*)Cout;
        float bcol[4];
#pragma unroll
        for (int j = 0; j < 4; ++j) bcol[j] = aux[n0 + j * 16 + lrow];
#pragma unroll
        for (int i = 0; i < 4; ++i) {
            u16* Crow = C + ((size_t)((m0 >> 4) + i) * (N >> 5) + (n0 >> 5)) * 512 + offl;
#pragma unroll
            for (int j = 0; j < 4; ++j) {
                u16* Cj = Crow + (j >> 1) * 512 + ((j & 1) << 8);
#pragma unroll
                for (int r = 0; r < 4; ++r)
                    Cj[r * 8] = f2bf(acc[i][j][r] + bcol[j]);
            }
        }
    } else if constexpr (MODE == 2) {          // row-bias, u16 brick
        u16* C = (u16*)Cout;
#pragma unroll
        for (int i = 0; i < 4; ++i) {
            const float4 b4 = *(const float4*)(aux + m0 + i * 16 + kq * 4);
            u16* Crow = C + ((size_t)((m0 >> 4) + i) * (N >> 5) + (n0 >> 5)) * 512 + offl;
#pragma unroll
            for (int j = 0; j < 4; ++j) {
                u16* Cj = Crow + (j >> 1) * 512 + ((j & 1) << 8);
                Cj[0]  = f2bf(acc[i][j][0] + b4.x);
                Cj[8]  = f2bf(acc[i][j][1] + b4.y);
                Cj[16] = f2bf(acc[i][j][2] + b4.z);
                Cj[24] = f2bf(acc[i][j][3] + b4.w);
            }
        }
    } else if constexpr (MODE == 3) {          // row-scale 1/rowsum, u16 brick
        u16* C = (u16*)Cout;
#pragma unroll
        for (int i = 0; i < 4; ++i) {
            const float4 rs4 = *(const float4*)(aux + m0 + i * 16 + kq * 4);
            const float inv0 = 1.0f / rs4.x, inv1 = 1.0f / rs4.y;
            const float inv2 = 1.0f / rs4.z, inv3 = 1.0f / rs4.w;
            u16* Crow = C + ((size_t)((m0 >> 4) + i) * (N >> 5) + (n0 >> 5)) * 512 + offl;
#pragma unroll
            for (int j = 0; j < 4; ++j) {
                u16* Cj = Crow + (j >> 1) * 512 + ((j & 1) << 8);
                Cj[0]  = f2bf(acc[i][j][0] * inv0);
                Cj[8]  = f2bf(acc[i][j][1] * inv1);
                Cj[16] = f2bf(acc[i][j][2] * inv2);
                Cj[24] = f2bf(acc[i][j][3] * inv3);
            }
        }
    } else {                                   // MODE 4: fp32 row-major + row bias
        float* C = (float*)Cout;
#pragma unroll
        for (int i = 0; i < 4; ++i) {
            const int row = m0 + i * 16 + kq * 4;
            const float4 b4 = *(const float4*)(aux + row);
            const float bv4[4] = {b4.x, b4.y, b4.z, b4.w};
#pragma unroll
            for (int r = 0; r < 4; ++r)
#pragma unroll
                for (int j = 0; j < 4; ++j)
                    C[(size_t)(row + r) * N + n0 + j * 16 + lrow] = acc[i][j][r] + bv4[r];
        }
    }
}

// =====================================================================
// Kernel 0a: weight cast fp32 -> bf16, BRICK output.
// =====================================================================
#define WQKV_SZ (OCH * CIN)
#define WO_SZ   (OCH * OCH)
#define CH_QKV  (WQKV_SZ / 8)
#define CH_WO   (WO_SZ / 8)
#define CH_TOT  (3 * CH_QKV + CH_WO)

__global__ __launch_bounds__(256) void prep_w_kernel(
    const float* __restrict__ Wq, const float* __restrict__ Wk,
    const float* __restrict__ Wv, const float* __restrict__ Wo,
    u16* __restrict__ Wqb, u16* __restrict__ Wkb,
    u16* __restrict__ Wvb, u16* __restrict__ Wob)
{
    int lc = blockIdx.x * 256 + threadIdx.x;
    if (lc >= CH_TOT) return;
    const float* src; u16* dst; int Kc;
    if      (lc < CH_QKV)     { src = Wq; dst = Wqb; Kc = CIN; }
    else if (lc < 2 * CH_QKV) { src = Wk; dst = Wkb; Kc = CIN; lc -= CH_QKV; }
    else if (lc < 3 * CH_QKV) { src = Wv; dst = Wvb; Kc = CIN; lc -= 2 * CH_QKV; }
    else                      { src = Wo; dst = Wob; Kc = OCH; lc -= 3 * CH_QKV; }
    const int brick = lc >> 6, l = lc & 63;
    const int bpr = Kc >> 5;
    const int g = brick / bpr, c = brick % bpr;
    const int row = g * 16 + (l & 15);
    const int col = c * 32 + (l >> 4) * 8;
    const float* s = src + (size_t)row * Kc + col;
    float4 v0 = *(const float4*)s;
    float4 v1 = *(const float4*)(s + 4);
    u16x8 o;
    o[0] = f2bf(v0.x); o[1] = f2bf(v0.y); o[2] = f2bf(v0.z); o[3] = f2bf(v0.w);
    o[4] = f2bf(v1.x); o[5] = f2bf(v1.y); o[6] = f2bf(v1.z); o[7] = f2bf(v1.w);
    *(u16x8*)(dst + (size_t)lc * 8) = o;
}

// =====================================================================
// Kernel 0b: transpose x [B,C,N] fp32 -> xT [B,N,C] bf16 BRICK.
// =====================================================================
__global__ __launch_bounds__(256) void transpose_x_kernel(
    const float* __restrict__ x, u16* __restrict__ xT)
{
    const int n0 = blockIdx.x * 64;
    const int c0 = blockIdx.y * 64;
    const int b  = blockIdx.z;
    const float* X = x + (size_t)b * CIN * NTOK;

    __shared__ float Ts[64][66];

    const int t = threadIdx.x;
#pragma unroll
    for (int rep = 0; rep < 4; ++rep) {
        const int cr = (t >> 4) + rep * 16;
        const int n4 = (t & 15) * 4;
        float4 v = *(const float4*)(X + (size_t)(c0 + cr) * NTOK + n0 + n4);
        *(float2*)&Ts[cr][n4]     = make_float2(v.x, v.y);
        *(float2*)&Ts[cr][n4 + 2] = make_float2(v.z, v.w);
    }
    __syncthreads();

    u16* O = xT + (size_t)b * NTOK * CIN;
#pragma unroll
    for (int rep = 0; rep < 2; ++rep) {
        const int nr = (t >> 3) + rep * 32;
        const int c8 = (t & 7) * 8;
        u16 tmp[8];
#pragma unroll
        for (int j = 0; j < 8; ++j) tmp[j] = f2bf(Ts[c8 + j][nr]);
        *(u16x8*)(O + baddr(n0 + nr, c0 + c8, CIN)) = *(const u16x8*)tmp;
    }
}

// =====================================================================
// Q/K/V merged, 1-wave 64x64 blocks (R14-verified)
// =====================================================================
__global__ __launch_bounds__(64) void qkv64_kernel(
    const u16* __restrict__ xT,
    const u16* __restrict__ Wqb, const float* __restrict__ bq,
    const u16* __restrict__ Wkb, const float* __restrict__ bk,
    const u16* __restrict__ Wvb, const float* __restrict__ bv,
    u16* __restrict__ Qt, u16* __restrict__ Kt, u16* __restrict__ Vw)
{
    __shared__ __align__(16) u16 sm[8192];
    const int sel = blockIdx.x % 24;            // b = bid%8 == XCD
    const int b = sel & 7, which = sel >> 3;
    const int rem = blockIdx.x / 24;            // 0..287
    const u16* xTb = xT + (size_t)b * NTOK * CIN;
    if (which < 2) {
        const int n0 = (rem & 7) * 64, m0 = (rem >> 3) * 64;
        gemm64_core<1, CIN>(sm, xTb, which ? Wkb : Wqb, which ? bk : bq,
            (which ? Kt : Qt) + (size_t)b * NTOK * OCH, OCH, m0, n0);
    } else {
        const int n0 = (rem % 36) * 64, m0 = (rem / 36) * 64;
        gemm64_core<2, CIN>(sm, Wvb, xTb, bv,
            Vw + (size_t)b * OCH * NTOK, NTOK, m0, n0);
    }
}

// =====================================================================
// Logits+exp, 1-wave 128x64 pipelined (R16): E = exp(SCALE * Qt.Kt^T),
// rowsumG += partial row sums.  12 brick loads -> 32 MFMA per BK=32
// step, vmcnt(12) counted wait, zero barriers (R14 mechanism).
// =====================================================================
__global__ __launch_bounds__(64) void logits1w_kernel(
    const u16* __restrict__ Qt, const u16* __restrict__ Kt,
    u16* __restrict__ Ew, float* __restrict__ rowsumG)
{
    __shared__ __align__(16) u16 sm[12288];     // 2 x (A 8 bricks + B 4 bricks)
    const int z = blockIdx.x & 7;               // batch == XCD
    const int rem = blockIdx.x >> 3;            // 0..647
    const int n0 = (rem % 36) * 64;             // Kt token tile (64)
    const int m0 = (rem / 36) * 128;            // Qt token tile (128)
    const u16* A  = Qt + (size_t)z * NTOK * OCH;
    const u16* Bp = Kt + (size_t)z * NTOK * OCH;

    const int ln = threadIdx.x & 63;
    const int lrow = ln & 15, kq = ln >> 4;

    constexpr int NT = OCH / 32;                // 16 steps
    constexpr int bpr = OCH >> 5;               // 16 bricks per row-group
    const size_t rstep = (size_t)bpr << 9;      // one brick-row in u16
    const u16* pA = A  + (((size_t)(m0 >> 4) * bpr) << 9) + (size_t)(ln << 3);
    const u16* pB = Bp + (((size_t)(n0 >> 4) * bpr) << 9) + (size_t)(ln << 3);

    u16* buf0 = sm;                             // A @0 (4096), B @4096 (2048)
    u16* buf1 = sm + 6144;

    f32x4 acc[8][4] = {};

#define STAGE12(ga, gb, Bf)                                                    \
    {                                                                          \
        u16* Ad = (Bf);                                                        \
        u16* Bd = (Bf) + 4096;                                                 \
        _Pragma("unroll")                                                      \
        for (int k_ = 0; k_ < 8; ++k_) gld16((ga) + k_ * rstep, Ad + k_ * 512);\
        _Pragma("unroll")                                                      \
        for (int k_ = 0; k_ < 4; ++k_) gld16((gb) + k_ * rstep, Bd + k_ * 512);\
    }

#define MFMA32(Bf)                                                             \
    {                                                                          \
        const u16* Ad = (Bf);                                                  \
        const u16* Bd = (Bf) + 4096;                                           \
        s16x8 a[8], b[4];                                                      \
        _Pragma("unroll")                                                      \
        for (int i_ = 0; i_ < 8; ++i_)                                         \
            a[i_] = *(const s16x8*)(Ad + ((i_ * 64) + kq * 16 + lrow) * 8);    \
        _Pragma("unroll")                                                      \
        for (int j_ = 0; j_ < 4; ++j_)                                         \
            b[j_] = *(const s16x8*)(Bd + ((j_ * 64) + kq * 16 + lrow) * 8);    \
        _Pragma("unroll")                                                      \
        for (int i_ = 0; i_ < 8; ++i_)                                         \
            _Pragma("unroll")                                                  \
            for (int j_ = 0; j_ < 4; ++j_)                                     \
                acc[i_][j_] = __builtin_amdgcn_mfma_f32_16x16x32_bf16(         \
                    a[i_], b[j_], acc[i_][j_], 0, 0, 0);                       \
    }

    STAGE12(pA, pB, buf0)                       // prologue: step 0

#pragma unroll 1
    for (int kt = 0; kt < NT; kt += 2) {
        STAGE12(pA + 512, pB + 512, buf1)       // step kt+1
        asm volatile("s_waitcnt vmcnt(12)" ::: "memory");  // step-kt done
        MFMA32(buf0)
        asm volatile("" ::: "memory");
        if (kt + 2 < NT) {
            STAGE12(pA + 1024, pB + 1024, buf0) // step kt+2
            asm volatile("s_waitcnt vmcnt(12)" ::: "memory");
        } else {
            asm volatile("s_waitcnt vmcnt(0)" ::: "memory");
        }
        MFMA32(buf1)
        asm volatile("" ::: "memory");
        pA += 1024; pB += 1024;
    }
#undef STAGE12
#undef MFMA32

    u16* E = Ew + (size_t)z * NTOK * NTOK;
    float* rsG = rowsumG + (size_t)z * NTOK;
    const int offl = ((lrow >> 3) << 7) + (lrow & 7) + (kq << 5);
#pragma unroll
    for (int i = 0; i < 8; ++i) {
        u16* Erow = E + ((size_t)((m0 >> 4) + i) * (NTOK >> 5) + (n0 >> 5)) * 512 + offl;
#pragma unroll
        for (int r = 0; r < 4; ++r) {
            float part = 0.f;
#pragma unroll
            for (int j = 0; j < 4; ++j) {
                float e = __expf(acc[i][j][r] * SCALE);
                part += e;
                Erow[(j >> 1) * 512 + ((j & 1) << 8) + r * 8] = f2bf(e);
            }
            part += __shfl_xor(part, 1);
            part += __shfl_xor(part, 2);
            part += __shfl_xor(part, 4);
            part += __shfl_xor(part, 8);
            if (lrow == 0) atomicAdd(&rsG[m0 + i * 16 + kq * 4 + r], part);
        }
    }
}

// =====================================================================
// PV and out, 1-wave 64x64 blocks (R14-verified)
// =====================================================================
__global__ __launch_bounds__(64) void pv64_kernel(
    const u16* __restrict__ Ew, const u16* __restrict__ Vw,
    const float* __restrict__ rowsumG, u16* __restrict__ AOt)
{
    __shared__ __align__(16) u16 sm[8192];
    const int z = blockIdx.x & 7;
    const int rem = blockIdx.x >> 3;            // 0..287
    const int n0 = (rem & 7) * 64, m0 = (rem >> 3) * 64;
    gemm64_core<3, NTOK>(sm, Ew + (size_t)z * NTOK * NTOK, Vw + (size_t)z * OCH * NTOK,
        rowsumG + (size_t)z * NTOK, AOt + (size_t)z * NTOK * OCH, OCH, m0, n0);
}

__global__ __launch_bounds__(64) void out64_kernel(
    const u16* __restrict__ Wob, const u16* __restrict__ AOt,
    const float* __restrict__ bo, float* __restrict__ out)
{
    __shared__ __align__(16) u16 sm[8192];
    const int z = blockIdx.x & 7;
    const int rem = blockIdx.x >> 3;            // 0..287
    const int n0 = (rem % 36) * 64, m0 = (rem / 36) * 64;
    gemm64_core<4, OCH>(sm, Wob, AOt + (size_t)z * NTOK * OCH, bo,
        out + (size_t)z * OCH * NTOK, NTOK, m0, n0);
}

// =====================================================================
extern "C" void kernel_launch(void* const* d_in, const int* in_sizes, int n_in,
                              void* d_out, int out_size, void* d_ws, size_t ws_size,
                              hipStream_t stream)
{
    const float* x  = (const float*)d_in[0];
    const float* Wq = (const float*)d_in[1];
    const float* bq = (const float*)d_in[2];
    const float* Wk = (const float*)d_in[3];
    const float* bk = (const float*)d_in[4];
    const float* Wv = (const float*)d_in[5];
    const float* bv = (const float*)d_in[6];
    const float* Wo = (const float*)d_in[7];
    const float* bo = (const float*)d_in[8];
    float* out = (float*)d_out;

    u16* ws = (u16*)d_ws;
    u16* Wqb = ws;
    u16* Wkb = Wqb + WQKV_SZ;
    u16* Wvb = Wkb + WQKV_SZ;
    u16* Wob = Wvb + WQKV_SZ;
    u16* xT  = Wob + WO_SZ;
    const size_t xtsz  = (size_t)B_ * NTOK * CIN;
    const size_t qkvsz = (size_t)B_ * NTOK * OCH;
    u16* Qt  = xT + xtsz;
    u16* Kt  = Qt + qkvsz;
    u16* Vw  = Kt + qkvsz;
    u16* Ew  = Vw + qkvsz;                          // B*N*N
    float* rowsumG = (float*)(Ew + (size_t)B_ * NTOK * NTOK);
    u16* AOt = Qt;                                  // alias: Qt dead after logits
    // total approx 157.5 MB

    dim3 blk(256), blk64(64);

    prep_w_kernel<<<dim3((CH_TOT + 255) / 256), blk, 0, stream>>>(
        Wq, Wk, Wv, Wo, Wqb, Wkb, Wvb, Wob);
    transpose_x_kernel<<<dim3(NTOK / 64, CIN / 64, B_), blk, 0, stream>>>(x, xT);
    hipMemsetAsync(rowsumG, 0, (size_t)B_ * NTOK * sizeof(float), stream);

    // Q + K + V merged: 288 tiles x 24 (which*8+batch) = 6912 blocks
    qkv64_kernel<<<dim3(288 * 24), blk64, 0, stream>>>(
        xT, Wqb, bq, Wkb, bk, Wvb, bv, Qt, Kt, Vw);

    // E = exp(scale * Qt.Kt^T), rowsum: 18 m-tiles x 36 n-tiles x 8 = 5184
    logits1w_kernel<<<dim3(648 * 8), blk64, 0, stream>>>(Qt, Kt, Ew, rowsumG);

    // AOt = (E.V^T)/rowsum: 36 tok-tiles x 8 o-tiles x 8 = 2304 blocks
    pv64_kernel<<<dim3(288 * 8), blk64, 0, stream>>>(Ew, Vw, rowsumG, AOt);

    // out = Wo.AOt + bo: 8 p-tiles x 36 tok-tiles x 8 = 2304 blocks
    out64_kernel<<<dim3(288 * 8), blk64, 0, stream>>>(Wob, AOt, bo, out);
}

// Round 10
// 270.209 us; speedup vs baseline: 1.2245x; 1.2245x over previous
//
#include <hip/hip_runtime.h>
#include <stdint.h>

// Problem constants (CorrelationModule): x[8,384,48,48], O=512, N=48*48=2304
#define B_    8
#define CIN   384
#define OCH   512
#define NTOK  2304
#define SCALE 0.044194173824159216f  // 1/sqrt(512)

typedef unsigned short u16;
typedef u16   u16x8 __attribute__((ext_vector_type(8)));
typedef short s16x8 __attribute__((ext_vector_type(8)));
typedef float f32x4 __attribute__((ext_vector_type(4)));

// ---------- bf16 helpers (bit-level, RNE) ----------
__device__ __forceinline__ u16 f2bf(float f) {
    union { uint32_t i; float f; } v; v.f = f;
    uint32_t r = v.i + 0x7fffu + ((v.i >> 16) & 1u);
    return (u16)(r >> 16);
}

// ---------- async global->LDS (width 16) ----------
typedef __attribute__((address_space(1))) const uint32_t glb_u32;
typedef __attribute__((address_space(3))) uint32_t lds_u32;

__device__ __forceinline__ void gld16(const u16* g, u16* l) {
    __builtin_amdgcn_global_load_lds((glb_u32*)g, (lds_u32*)l, 16, 0, 0);
}

// =====================================================================
// BRICK FORMAT for all bf16 intermediates.
// brick (g, c) = rows g*16..+16, cols c*32..+32, 512 u16, chunk l (16 B)
// = (col8 = l>>4, row = l&15).  u16 offset of (row, col) inside brick:
//   ((col>>3)&3)*128 + (row&15)*8 + (col&7)
//
// R17 structure-selection rule (HW-derived over R13-R16):
//  - SHORT-K / fill-bound GEMMs (qkv K=384, out K=512 with 2304 blocks):
//    1-wave 64^2 barrier-free counted-vmcnt blocks (R14-verified).
//  - LONG-K GEMMs (logits K=512@2592blk, pv K=2304): 4-wave 128^2
//    2-barrier blocks — higher staging AI (64 vs 32 flop/byte) and
//    residency; 1-wave big tiles collapse occupancy (R16: 8.7%).
// logits: R15-verified 72.5 µs kernel.  pv: R13-verified 128^2 kernel.
// prep_w + transpose fused into one launch (pure index remap).
// =====================================================================
__device__ __forceinline__ size_t baddr(int row, int col, int Kc) {
    return ((size_t)(row >> 4) * (Kc >> 5) + (col >> 5)) * 512
         + (size_t)(((col >> 3) & 3) * 128 + (row & 15) * 8 + (col & 7));
}

// stage a 128x32 brick-format tile (rows row0..+128, cols k0..+32) into LDS
__device__ __forceinline__ void stage_blocked(const u16* __restrict__ base,
                                              int row0, int k0, int Kc,
                                              u16* __restrict__ dst, int t)
{
    const int lane = t & 63;
    const int w = t >> 6;
    const int bpr = Kc >> 5;
#pragma unroll
    for (int it = 0; it < 2; ++it) {
        const int ck = w * 2 + it;               // 0..7 (16-row groups)
        const u16* gp = base + ((size_t)((row0 >> 4) + ck) * bpr + (k0 >> 5)) * 512
                      + (size_t)lane * 8;
        u16* lp = dst + ck * 512;                // wave-uniform base
        __builtin_amdgcn_global_load_lds((glb_u32*)gp, (lds_u32*)lp, 16, 0, 0);
    }
}

// 16x16x32 MFMA core on brick buffers (proven R6/R7 algebra)
__device__ __forceinline__ void mfma_core(const u16* __restrict__ As,
                                          const u16* __restrict__ Bs,
                                          int wm16, int wn16, int lrow, int kq,
                                          f32x4 acc[4][4])
{
    s16x8 a[4], b[4];
#pragma unroll
    for (int i = 0; i < 4; ++i)
        a[i] = *(const s16x8*)(As + (((wm16 + i) * 64) + kq * 16 + lrow) * 8);
#pragma unroll
    for (int j = 0; j < 4; ++j)
        b[j] = *(const s16x8*)(Bs + (((wn16 + j) * 64) + kq * 16 + lrow) * 8);
#pragma unroll
    for (int i = 0; i < 4; ++i)
#pragma unroll
        for (int j = 0; j < 4; ++j)
            acc[i][j] = __builtin_amdgcn_mfma_f32_16x16x32_bf16(a[i], b[j], acc[i][j], 0, 0, 0);
}

// =====================================================================
// 1-wave 64x64 GEMM core (R14-verified).  MODE: 1 = +bias[col] (Q/K),
// 2 = +bias[row] (V), 4 = fp32 +bias[row] (out)
// =====================================================================
template <int MODE, int K>
__device__ __forceinline__ void gemm64_core(
    u16* __restrict__ sm,
    const u16* __restrict__ A, const u16* __restrict__ Bp,
    const float* __restrict__ aux, void* __restrict__ Cout,
    int N, int m0, int n0)
{
    constexpr int NT = K / 32;                 // 12 / 16 — even
    u16* As0 = sm;
    u16* Bs0 = sm + 2048;
    u16* As1 = sm + 4096;
    u16* Bs1 = sm + 6144;

    const int ln = threadIdx.x & 63;
    const int lrow = ln & 15, kq = ln >> 4;

    const int bpr = K >> 5;
    const size_t rstep = (size_t)bpr << 9;     // one brick-row in u16
    const u16* pA = A  + (((size_t)(m0 >> 4) * bpr) << 9) + (size_t)(ln << 3);
    const u16* pB = Bp + (((size_t)(n0 >> 4) * bpr) << 9) + (size_t)(ln << 3);

    f32x4 acc[4][4] = {};

#define STAGE8(ga, gb, Ad, Bd)                                             \
    gld16((ga),             (Ad));        gld16((ga) + rstep,     (Ad) + 512);  \
    gld16((ga) + 2 * rstep, (Ad) + 1024); gld16((ga) + 3 * rstep, (Ad) + 1536); \
    gld16((gb),             (Bd));        gld16((gb) + rstep,     (Bd) + 512);  \
    gld16((gb) + 2 * rstep, (Bd) + 1024); gld16((gb) + 3 * rstep, (Bd) + 1536);

    STAGE8(pA, pB, As0, Bs0)                   // prologue: step 0 -> buf0

#pragma unroll 1
    for (int kt = 0; kt < NT; kt += 2) {
        STAGE8(pA + 512, pB + 512, As1, Bs1)   // step kt+1 -> buf1
        asm volatile("s_waitcnt vmcnt(8)" ::: "memory");   // step-kt loads done
        mfma_core(As0, Bs0, 0, 0, lrow, kq, acc);
        asm volatile("" ::: "memory");
        if (kt + 2 < NT) {
            STAGE8(pA + 1024, pB + 1024, As0, Bs0)         // step kt+2 -> buf0
            asm volatile("s_waitcnt vmcnt(8)" ::: "memory");
        } else {
            asm volatile("s_waitcnt vmcnt(0)" ::: "memory");
        }
        mfma_core(As1, Bs1, 0, 0, lrow, kq, acc);
        asm volatile("" ::: "memory");
        pA += 1024; pB += 1024;
    }
#undef STAGE8

    const int offl = ((lrow >> 3) << 7) + (lrow & 7) + (kq << 5);

    if constexpr (MODE == 1) {                 // col-bias, u16 brick
        u16* C = (u16*)Cout;
        float bcol[4];
#pragma unroll
        for (int j = 0; j < 4; ++j) bcol[j] = aux[n0 + j * 16 + lrow];
#pragma unroll
        for (int i = 0; i < 4; ++i) {
            u16* Crow = C + ((size_t)((m0 >> 4) + i) * (N >> 5) + (n0 >> 5)) * 512 + offl;
#pragma unroll
            for (int j = 0; j < 4; ++j) {
                u16* Cj = Crow + (j >> 1) * 512 + ((j & 1) << 8);
#pragma unroll
                for (int r = 0; r < 4; ++r)
                    Cj[r * 8] = f2bf(acc[i][j][r] + bcol[j]);
            }
        }
    } else if constexpr (MODE == 2) {          // row-bias, u16 brick
        u16* C = (u16*)Cout;
#pragma unroll
        for (int i = 0; i < 4; ++i) {
            const float4 b4 = *(const float4*)(aux + m0 + i * 16 + kq * 4);
            u16* Crow = C + ((size_t)((m0 >> 4) + i) * (N >> 5) + (n0 >> 5)) * 512 + offl;
#pragma unroll
            for (int j = 0; j < 4; ++j) {
                u16* Cj = Crow + (j >> 1) * 512 + ((j & 1) << 8);
                Cj[0]  = f2bf(acc[i][j][0] + b4.x);
                Cj[8]  = f2bf(acc[i][j][1] + b4.y);
                Cj[16] = f2bf(acc[i][j][2] + b4.z);
                Cj[24] = f2bf(acc[i][j][3] + b4.w);
            }
        }
    } else {                                   // MODE 4: fp32 row-major + row bias
        float* C = (float*)Cout;
#pragma unroll
        for (int i = 0; i < 4; ++i) {
            const int row = m0 + i * 16 + kq * 4;
            const float4 b4 = *(const float4*)(aux + row);
            const float bv4[4] = {b4.x, b4.y, b4.z, b4.w};
#pragma unroll
            for (int r = 0; r < 4; ++r)
#pragma unroll
                for (int j = 0; j < 4; ++j)
                    C[(size_t)(row + r) * N + n0 + j * 16 + lrow] = acc[i][j][r] + bv4[r];
        }
    }
}

// =====================================================================
// Kernel 0: fused weight-cast (fp32->bf16 brick) + x transpose.
// Blocks [0, PREP_BLK): prep path.  Blocks [PREP_BLK, ..): transpose.
// Both paths byte-identical to the R13/R15-verified standalone kernels.
// =====================================================================
#define WQKV_SZ (OCH * CIN)
#define WO_SZ   (OCH * OCH)
#define CH_QKV  (WQKV_SZ / 8)
#define CH_WO   (WO_SZ / 8)
#define CH_TOT  (3 * CH_QKV + CH_WO)
#define PREP_BLK (CH_TOT / 256)                 // 416 exactly
#define TRX_BLK  ((NTOK / 64) * (CIN / 64) * B_)  // 1728

__global__ __launch_bounds__(256) void prep_kernel(
    const float* __restrict__ Wq, const float* __restrict__ Wk,
    const float* __restrict__ Wv, const float* __restrict__ Wo,
    u16* __restrict__ Wqb, u16* __restrict__ Wkb,
    u16* __restrict__ Wvb, u16* __restrict__ Wob,
    const float* __restrict__ x, u16* __restrict__ xT)
{
    __shared__ float Ts[64][66];
    const int t = threadIdx.x;

    if (blockIdx.x < PREP_BLK) {
        int lc = blockIdx.x * 256 + t;
        const float* src; u16* dst; int Kc;
        if      (lc < CH_QKV)     { src = Wq; dst = Wqb; Kc = CIN; }
        else if (lc < 2 * CH_QKV) { src = Wk; dst = Wkb; Kc = CIN; lc -= CH_QKV; }
        else if (lc < 3 * CH_QKV) { src = Wv; dst = Wvb; Kc = CIN; lc -= 2 * CH_QKV; }
        else                      { src = Wo; dst = Wob; Kc = OCH; lc -= 3 * CH_QKV; }
        const int brick = lc >> 6, l = lc & 63;
        const int bpr = Kc >> 5;
        const int g = brick / bpr, c = brick % bpr;
        const int row = g * 16 + (l & 15);
        const int col = c * 32 + (l >> 4) * 8;
        const float* s = src + (size_t)row * Kc + col;
        float4 v0 = *(const float4*)s;
        float4 v1 = *(const float4*)(s + 4);
        u16x8 o;
        o[0] = f2bf(v0.x); o[1] = f2bf(v0.y); o[2] = f2bf(v0.z); o[3] = f2bf(v0.w);
        o[4] = f2bf(v1.x); o[5] = f2bf(v1.y); o[6] = f2bf(v1.z); o[7] = f2bf(v1.w);
        *(u16x8*)(dst + (size_t)lc * 8) = o;
        return;
    }

    const int tb = blockIdx.x - PREP_BLK;       // 0..1727
    const int n0 = (tb % 36) * 64;
    const int c0 = ((tb / 36) % 6) * 64;
    const int b  = tb / 216;
    const float* X = x + (size_t)b * CIN * NTOK;

#pragma unroll
    for (int rep = 0; rep < 4; ++rep) {
        const int cr = (t >> 4) + rep * 16;
        const int n4 = (t & 15) * 4;
        float4 v = *(const float4*)(X + (size_t)(c0 + cr) * NTOK + n0 + n4);
        *(float2*)&Ts[cr][n4]     = make_float2(v.x, v.y);
        *(float2*)&Ts[cr][n4 + 2] = make_float2(v.z, v.w);
    }
    __syncthreads();

    u16* O = xT + (size_t)b * NTOK * CIN;
#pragma unroll
    for (int rep = 0; rep < 2; ++rep) {
        const int nr = (t >> 3) + rep * 32;
        const int c8 = (t & 7) * 8;
        u16 tmp[8];
#pragma unroll
        for (int j = 0; j < 8; ++j) tmp[j] = f2bf(Ts[c8 + j][nr]);
        *(u16x8*)(O + baddr(n0 + nr, c0 + c8, CIN)) = *(const u16x8*)tmp;
    }
}

// =====================================================================
// Q/K/V merged, 1-wave 64x64 blocks (R14-verified)
// =====================================================================
__global__ __launch_bounds__(64) void qkv64_kernel(
    const u16* __restrict__ xT,
    const u16* __restrict__ Wqb, const float* __restrict__ bq,
    const u16* __restrict__ Wkb, const float* __restrict__ bk,
    const u16* __restrict__ Wvb, const float* __restrict__ bv,
    u16* __restrict__ Qt, u16* __restrict__ Kt, u16* __restrict__ Vw)
{
    __shared__ __align__(16) u16 sm[8192];
    const int sel = blockIdx.x % 24;            // b = bid%8 == XCD
    const int b = sel & 7, which = sel >> 3;
    const int rem = blockIdx.x / 24;            // 0..287
    const u16* xTb = xT + (size_t)b * NTOK * CIN;
    if (which < 2) {
        const int n0 = (rem & 7) * 64, m0 = (rem >> 3) * 64;
        gemm64_core<1, CIN>(sm, xTb, which ? Wkb : Wqb, which ? bk : bq,
            (which ? Kt : Qt) + (size_t)b * NTOK * OCH, OCH, m0, n0);
    } else {
        const int n0 = (rem % 36) * 64, m0 = (rem / 36) * 64;
        gemm64_core<2, CIN>(sm, Wvb, xTb, bv,
            Vw + (size_t)b * OCH * NTOK, NTOK, m0, n0);
    }
}

// =====================================================================
// Logits+exp kernel (R15-verified 128^2 4-wave — 72.5 µs):
// E[n][m] = exp(SCALE * Qt[n].Kt[m]); rowsumG += row sums.
// =====================================================================
__global__ __launch_bounds__(256) void logits_exp_kernel(
    const u16* __restrict__ Qt, const u16* __restrict__ Kt,
    u16* __restrict__ Ew, float* __restrict__ rowsumG)
{
    const int z   = blockIdx.x % B_;
    const int rem = blockIdx.x / B_;
    const int n0 = (rem % (NTOK / 128)) * 128;   // Kt token tiles, fast
    const int m0 = (rem / (NTOK / 128)) * 128;   // Qt token tiles
    const u16* A  = Qt + (size_t)z * NTOK * OCH;
    const u16* Bp = Kt + (size_t)z * NTOK * OCH;

    __shared__ u16 As[128 * 32];
    __shared__ u16 Bs[128 * 32];
    __shared__ float rowsumL[128];

    const int t = threadIdx.x;
    const int w = t >> 6, ln = t & 63;
    const int wm16 = (w & 1) * 4, wn16 = (w >> 1) * 4;
    const int lrow = ln & 15, kq = ln >> 4;

    if (t < 128) rowsumL[t] = 0.f;

    f32x4 acc[4][4] = {};

    for (int k0 = 0; k0 < OCH; k0 += 32) {
        stage_blocked(A, m0, k0, OCH, As, t);
        stage_blocked(Bp, n0, k0, OCH, Bs, t);
        __syncthreads();
        mfma_core(As, Bs, wm16, wn16, lrow, kq, acc);
        __syncthreads();
    }

    u16* E = Ew + (size_t)z * NTOK * NTOK;
    const int offl = ((lrow >> 3) << 7) + (lrow & 7) + (kq << 5);
#pragma unroll
    for (int i = 0; i < 4; ++i) {
        u16* Erow = E + ((size_t)((m0 >> 4) + wm16 + i) * (NTOK >> 5) + (n0 >> 5)) * 512 + offl;
#pragma unroll
        for (int r = 0; r < 4; ++r) {
            float part = 0.f;
#pragma unroll
            for (int j = 0; j < 4; ++j) {
                float e = __expf(acc[i][j][r] * SCALE);
                part += e;
                Erow[((wn16 + j) >> 1) * 512 + ((j & 1) << 8) + r * 8] = f2bf(e);
            }
            part += __shfl_xor(part, 1);
            part += __shfl_xor(part, 2);
            part += __shfl_xor(part, 4);
            part += __shfl_xor(part, 8);
            if (lrow == 0) atomicAdd(&rowsumL[(wm16 + i) * 16 + kq * 4 + r], part);
        }
    }
    __syncthreads();
    if (t < 128) atomicAdd(&rowsumG[(size_t)z * NTOK + m0 + t], rowsumL[t]);
}

// =====================================================================
// PV kernel (R13-verified 128^2 4-wave, K=2304 — long-K rule):
// AOt[n][o] = (sum_m E[n][m]*V[o][m]) / rowsum
// =====================================================================
__global__ __launch_bounds__(256) void pv_div_kernel(
    const u16* __restrict__ Ew, const u16* __restrict__ Vw,
    const float* __restrict__ rowsumG, u16* __restrict__ AOt)
{
    const int z   = blockIdx.x % B_;
    const int rem = blockIdx.x / B_;
    const int n0 = (rem % 4) * 128;              // o tiles, fast
    const int m0 = (rem / 4) * 128;              // token tiles
    const u16* A  = Ew + (size_t)z * NTOK * NTOK;
    const u16* Bp = Vw + (size_t)z * OCH * NTOK;

    __shared__ u16 As[128 * 32];
    __shared__ u16 Bs[128 * 32];

    const int t = threadIdx.x;
    const int w = t >> 6, ln = t & 63;
    const int wm16 = (w & 1) * 4, wn16 = (w >> 1) * 4;
    const int lrow = ln & 15, kq = ln >> 4;

    f32x4 acc[4][4] = {};

    for (int k0 = 0; k0 < NTOK; k0 += 32) {
        stage_blocked(A, m0, k0, NTOK, As, t);
        stage_blocked(Bp, n0, k0, NTOK, Bs, t);
        __syncthreads();
        mfma_core(As, Bs, wm16, wn16, lrow, kq, acc);
        __syncthreads();
    }

    u16* AO = AOt + (size_t)z * NTOK * OCH;
    const int offl = ((lrow >> 3) << 7) + (lrow & 7) + (kq << 5);
#pragma unroll
    for (int i = 0; i < 4; ++i) {
        const float4 rs4 = *(const float4*)(rowsumG + (size_t)z * NTOK + m0 + (wm16 + i) * 16 + kq * 4);
        const float inv0 = 1.0f / rs4.x, inv1 = 1.0f / rs4.y;
        const float inv2 = 1.0f / rs4.z, inv3 = 1.0f / rs4.w;
        u16* Crow = AO + ((size_t)((m0 >> 4) + wm16 + i) * (OCH >> 5) + (n0 >> 5)) * 512 + offl;
#pragma unroll
        for (int j = 0; j < 4; ++j) {
            u16* Cj = Crow + ((wn16 + j) >> 1) * 512 + ((j & 1) << 8);
            Cj[0]  = f2bf(acc[i][j][0] * inv0);
            Cj[8]  = f2bf(acc[i][j][1] * inv1);
            Cj[16] = f2bf(acc[i][j][2] * inv2);
            Cj[24] = f2bf(acc[i][j][3] * inv3);
        }
    }
}

// =====================================================================
// out, 1-wave 64x64 blocks (R14-verified)
// =====================================================================
__global__ __launch_bounds__(64) void out64_kernel(
    const u16* __restrict__ Wob, const u16* __restrict__ AOt,
    const float* __restrict__ bo, float* __restrict__ out)
{
    __shared__ __align__(16) u16 sm[8192];
    const int z = blockIdx.x & 7;
    const int rem = blockIdx.x >> 3;            // 0..287
    const int n0 = (rem % 36) * 64, m0 = (rem / 36) * 64;
    gemm64_core<4, OCH>(sm, Wob, AOt + (size_t)z * NTOK * OCH, bo,
        out + (size_t)z * OCH * NTOK, NTOK, m0, n0);
}

// =====================================================================
extern "C" void kernel_launch(void* const* d_in, const int* in_sizes, int n_in,
                              void* d_out, int out_size, void* d_ws, size_t ws_size,
                              hipStream_t stream)
{
    const float* x  = (const float*)d_in[0];
    const float* Wq = (const float*)d_in[1];
    const float* bq = (const float*)d_in[2];
    const float* Wk = (const float*)d_in[3];
    const float* bk = (const float*)d_in[4];
    const float* Wv = (const float*)d_in[5];
    const float* bv = (const float*)d_in[6];
    const float* Wo = (const float*)d_in[7];
    const float* bo = (const float*)d_in[8];
    float* out = (float*)d_out;

    u16* ws = (u16*)d_ws;
    u16* Wqb = ws;
    u16* Wkb = Wqb + WQKV_SZ;
    u16* Wvb = Wkb + WQKV_SZ;
    u16* Wob = Wvb + WQKV_SZ;
    u16* xT  = Wob + WO_SZ;
    const size_t xtsz  = (size_t)B_ * NTOK * CIN;
    const size_t qkvsz = (size_t)B_ * NTOK * OCH;
    u16* Qt  = xT + xtsz;
    u16* Kt  = Qt + qkvsz;
    u16* Vw  = Kt + qkvsz;
    u16* Ew  = Vw + qkvsz;                          // B*N*N
    float* rowsumG = (float*)(Ew + (size_t)B_ * NTOK * NTOK);
    u16* AOt = Qt;                                  // alias: Qt dead after logits
    // total approx 157.5 MB

    dim3 blk(256), blk64(64);

    hipMemsetAsync(rowsumG, 0, (size_t)B_ * NTOK * sizeof(float), stream);

    // fused weight-cast + x-transpose: 416 + 1728 = 2144 blocks
    prep_kernel<<<dim3(PREP_BLK + TRX_BLK), blk, 0, stream>>>(
        Wq, Wk, Wv, Wo, Wqb, Wkb, Wvb, Wob, x, xT);

    // Q + K + V merged: 288 tiles x 24 (which*8+batch) = 6912 blocks
    qkv64_kernel<<<dim3(288 * 24), blk64, 0, stream>>>(
        xT, Wqb, bq, Wkb, bk, Wvb, bv, Qt, Kt, Vw);

    // E = exp(scale * Qt.Kt^T), rowsumG += row sums  (18x18x8 = 2592)
    logits_exp_kernel<<<dim3(18 * 18 * B_), blk, 0, stream>>>(Qt, Kt, Ew, rowsumG);

    // AOt = (E.V^T) / rowsum: 4 o-tiles (fast) x 18 token-tiles x 8 = 576
    pv_div_kernel<<<dim3(4 * 18 * B_), blk, 0, stream>>>(Ew, Vw, rowsumG, AOt);

    // out = Wo.AOt + bo: 8 p-tiles x 36 tok-tiles x 8 = 2304 blocks
    out64_kernel<<<dim3(288 * 8), blk64, 0, stream>>>(Wob, AOt, bo, out);
}